// Round 13
// baseline (617.234 us; speedup 1.0000x reference)
//
#include <hip/hip_runtime.h>
#include <stdint.h>

typedef __bf16 bf16x8 __attribute__((ext_vector_type(8)));
typedef float f32x4 __attribute__((ext_vector_type(4)));
typedef unsigned short u16x8 __attribute__((ext_vector_type(8)));
typedef unsigned long long ull_t;
typedef unsigned short ushort_t;

#define DEV __device__ __forceinline__

DEV unsigned short f2bf(float f) {
  __bf16 b = (__bf16)f;
  return __builtin_bit_cast(unsigned short, b);
}

DEV float bf2f(unsigned short b) { return __uint_as_float((unsigned int)b << 16); }

DEV f32x4 zero4() { f32x4 z = {0.f, 0.f, 0.f, 0.f}; return z; }

DEV float softplusf(float v) { return (v > 15.f) ? v : log1pf(expf(v)); }

// Pack W[K][Ncols] (f32 row-major) -> fragment-major bf16 (split-4 k-layout).
DEV void pack_dev(const float* __restrict__ W, unsigned short* __restrict__ P,
                  int Ncols, int permk, int idx) {
  int j = idx & 7;
  int lane = (idx >> 3) & 63;
  int rest = idx >> 9;
  int NT = Ncols >> 4;
  int nt = rest % NT;
  int kt = rest / NT;
  int k = kt * 32 + ((j >> 2) * 16) + ((lane >> 4) * 4) + (j & 3);
  if (permk) k = (k & ~63) | ((k & 3) << 4) | ((k >> 2) & 15);
  int col = nt * 16 + (lane & 15);
  P[idx] = f2bf(W[(size_t)k * Ncols + col]);
}

// Fused prologue: 5 weight packs + x->bf16 cvt + degree count, role-split by block.
// Block ranges: c1[0,64) e1[64,256) e2[256,512) c2[512,1024) c3[1024,1088)
//               cvt[1088,1088+nb_cvt) deg[.., +nb_deg)
__global__ __launch_bounds__(256) void k_prologue(
    const float* __restrict__ c1W, unsigned short* __restrict__ p_c1,
    const float* __restrict__ eW1, unsigned short* __restrict__ p_e1,
    const float* __restrict__ eW2, unsigned short* __restrict__ p_e2,
    const float* __restrict__ c2W, unsigned short* __restrict__ p_c2,
    const float* __restrict__ c3W, unsigned short* __restrict__ p_c3,
    const float* __restrict__ x, ushort_t* __restrict__ xb,
    const int* __restrict__ dsts, int* __restrict__ degi,
    int n4, int E, int nb_cvt) {
  const int b = blockIdx.x;
  const int tid = threadIdx.x;
  if (b < 64) {
    pack_dev(c1W, p_c1, 256, 0, b * 256 + tid);
  } else if (b < 256) {
    pack_dev(eW1, p_e1, 256, 0, (b - 64) * 256 + tid);
  } else if (b < 512) {
    pack_dev(eW2, p_e2, 256, 1, (b - 256) * 256 + tid);
  } else if (b < 1024) {
    pack_dev(c2W, p_c2, 256, 0, (b - 512) * 256 + tid);
  } else if (b < 1088) {
    pack_dev(c3W, p_c3, 64, 0, (b - 1024) * 256 + tid);
  } else if (b < 1088 + nb_cvt) {
    int i = (b - 1088) * 256 + tid;
    if (i < n4) {
      float4 v = *(const float4*)(x + (size_t)i * 4);
      ushort4 u;
      u.x = f2bf(v.x); u.y = f2bf(v.y); u.z = f2bf(v.z); u.w = f2bf(v.w);
      *(ushort4*)(xb + (size_t)i * 4) = u;
    }
  } else {
    int i = (b - 1088 - nb_cvt) * 256 + tid;
    if (i < E) atomicAdd(&degi[dsts[i]], 1);
  }
}

// Single-block exclusive scan + dis = rsqrt(deg+1).
__global__ __launch_bounds__(1024) void k_scan_dis(const int* __restrict__ degi,
                                                   int* __restrict__ ptr,
                                                   float* __restrict__ dis, int n) {
  __shared__ int part[1024];
  const int tid = threadIdx.x;
  const int chunk = (n + 1023) / 1024;
  const int b = tid * chunk;
  const int e2 = min(n, b + chunk);
  int s = 0;
  for (int i = b; i < e2; ++i) {
    int d = degi[i];
    dis[i] = rsqrtf((float)d + 1.0f);
    s += d;
  }
  part[tid] = s;
  __syncthreads();
  for (int off = 1; off < 1024; off <<= 1) {
    int val = (tid >= off) ? part[tid - off] : 0;
    __syncthreads();
    part[tid] += val;
    __syncthreads();
  }
  int run = (tid == 0) ? 0 : part[tid - 1];
  for (int i = b; i < e2; ++i) {
    ptr[i] = run;
    run += degi[i];
  }
  if (tid == 1023) ptr[n] = run;
}

// Counting-sort fill: edges grouped by dst; store (src, dis[src]*dis[dst]).
__global__ void k_fill(const int* __restrict__ srcs, const int* __restrict__ dsts,
                       const int* __restrict__ ptr, const float* __restrict__ dis,
                       int* __restrict__ fillc,
                       int2* __restrict__ sc_s, int* __restrict__ dst_s,
                       int* __restrict__ perm_s, int E) {
  int e = blockIdx.x * 256 + threadIdx.x;
  if (e >= E) return;
  int d = dsts[e];
  int s = srcs[e];
  int pos = ptr[d] + atomicAdd(&fillc[d], 1);
  float c = dis[s] * dis[d];
  sc_s[pos] = make_int2(s, __float_as_int(c));
  dst_s[pos] = d;
  perm_s[pos] = e;
}

// Per-node CSR gather: acc = sum_{e in N(v)} feat[src_e]*c_e, 4-deep unrolled.
// FINALIZE: out = relu(acc + hw[v]*dis[v]^2 + bias).  INBF16: feat/hw are bf16.
template <int COLS, bool FINALIZE, bool INBF16>
__global__ __launch_bounds__(256) void k_gather_agg(
    const void* __restrict__ featv, const int2* __restrict__ sc,
    const int* __restrict__ ptr, const float* __restrict__ dis,
    const void* __restrict__ hwv, const float* __restrict__ bias,
    float* __restrict__ out, int n) {
  constexpr int V = COLS / 64;
  const int v = blockIdx.x * 4 + (threadIdx.x >> 6);
  if (v >= n) return;
  const int lane = threadIdx.x & 63;
  const int beg = ptr[v], end = ptr[v + 1];

  auto loadrow = [&](int s, float* f) {
    if constexpr (INBF16) {
      const ushort_t* feat = (const ushort_t*)featv;
      if constexpr (V == 4) {
        ushort4 u = *(const ushort4*)(feat + (size_t)s * COLS + lane * 4);
        f[0] = bf2f(u.x); f[1] = bf2f(u.y); f[2] = bf2f(u.z); f[3] = bf2f(u.w);
      } else {
        f[0] = bf2f(feat[(size_t)s * COLS + lane]);
      }
    } else {
      const float* feat = (const float*)featv;
      if constexpr (V == 4) {
        float4 q = *(const float4*)(feat + (size_t)s * COLS + lane * 4);
        f[0] = q.x; f[1] = q.y; f[2] = q.z; f[3] = q.w;
      } else {
        f[0] = feat[(size_t)s * COLS + lane];
      }
    }
  };

  float acc[V];
#pragma unroll
  for (int i = 0; i < V; ++i) acc[i] = 0.f;
  const int cnt = end - beg;
  const int2* scp = sc + beg;
  int i = 0;
  for (; i + 4 <= cnt; i += 4) {
    int2 s0 = scp[i], s1 = scp[i + 1], s2 = scp[i + 2], s3 = scp[i + 3];
    float f0[V], f1[V], f2[V], f3[V];
    loadrow(s0.x, f0); loadrow(s1.x, f1); loadrow(s2.x, f2); loadrow(s3.x, f3);
    float c0 = __int_as_float(s0.y), c1 = __int_as_float(s1.y);
    float c2 = __int_as_float(s2.y), c3 = __int_as_float(s3.y);
#pragma unroll
    for (int j = 0; j < V; ++j)
      acc[j] += f0[j] * c0 + f1[j] * c1 + f2[j] * c2 + f3[j] * c3;
  }
  for (; i < cnt; ++i) {
    int2 s0 = scp[i];
    float c0 = __int_as_float(s0.y);
    float f0[V];
    loadrow(s0.x, f0);
#pragma unroll
    for (int j = 0; j < V; ++j) acc[j] += f0[j] * c0;
  }
  float* op = out + (size_t)v * COLS + lane * V;
  if constexpr (FINALIZE) {
    const float dv = dis[v];
    float d2 = dv * dv;
    float h[V];
    if constexpr (INBF16) {
      const ushort_t* hw = (const ushort_t*)hwv;
      if constexpr (V == 4) {
        ushort4 u = *(const ushort4*)(hw + (size_t)v * COLS + lane * 4);
        h[0] = bf2f(u.x); h[1] = bf2f(u.y); h[2] = bf2f(u.z); h[3] = bf2f(u.w);
      } else {
        h[0] = bf2f(hw[(size_t)v * COLS + lane]);
      }
    } else {
      const float* hw = (const float*)hwv;
      if constexpr (V == 4) {
        float4 q = *(const float4*)(hw + (size_t)v * COLS + lane * 4);
        h[0] = q.x; h[1] = q.y; h[2] = q.z; h[3] = q.w;
      } else {
        h[0] = hw[(size_t)v * COLS + lane];
      }
    }
#pragma unroll
    for (int i2 = 0; i2 < V; ++i2)
      acc[i2] = fmaxf(acc[i2] + h[i2] * d2 + bias[lane * V + i2], 0.f);
  }
  if constexpr (V == 4) {
    *(float4*)op = make_float4(acc[0], acc[1], acc[2], acc[3]);
  } else {
    op[0] = acc[0];
  }
}

// Generic node GEMM: out[r,:NOUT] = inA[r,:K] (+inB[r,:K]*dis[r]^2) @ Wp (+bias, relu)
template <int K, int NOUT, bool COMPOSE, bool RELUBIAS, bool OUTBF16>
__global__ __launch_bounds__(256, 2) void gcn_gemm(
    const float* __restrict__ inA, const float* __restrict__ inB,
    const float* __restrict__ dis,
    const unsigned short* __restrict__ Wp, const float* __restrict__ bias,
    void* __restrict__ outv, int out_stride, int nrows) {
  constexpr int NT = NOUT / 16;
  constexpr int NTW = NOUT / 64;
  __shared__ unsigned short s_in[64 * K];
  const int tid = threadIdx.x;
  const int r0 = blockIdx.x * 64;

  constexpr int C4R = K / 4;
  for (int idx = tid; idx < 64 * C4R; idx += 256) {
    int row = idx / C4R;
    int rem = idx - row * C4R;
    int grow = r0 + row;
    float4 v = make_float4(0.f, 0.f, 0.f, 0.f);
    if (grow < nrows) {
      v = *(const float4*)&inA[(size_t)grow * K + rem * 4];
      if constexpr (COMPOSE) {
        float d = dis[grow];
        d *= d;
        float4 w2 = *(const float4*)&inB[(size_t)grow * K + rem * 4];
        v.x += w2.x * d; v.y += w2.y * d; v.z += w2.z * d; v.w += w2.w * d;
      }
    }
    ushort4 b;
    b.x = f2bf(v.x); b.y = f2bf(v.y); b.z = f2bf(v.z); b.w = f2bf(v.w);
    *(ushort4*)&s_in[row * K + ((rem ^ (row & 7)) * 4)] = b;
  }
  __syncthreads();

  const int lane = tid & 63, wid = tid >> 6;
  const int lr = lane & 15, lg = lane >> 4;
  f32x4 acc[4][NTW];
#pragma unroll
  for (int m = 0; m < 4; ++m)
#pragma unroll
    for (int n2 = 0; n2 < NTW; ++n2) acc[m][n2] = zero4();

#pragma unroll
  for (int kt = 0; kt < K / 32; ++kt) {
    bf16x8 a[4];
#pragma unroll
    for (int m = 0; m < 4; ++m) {
      int rA = m * 16 + lr;
      int c1 = (kt * 8 + lg) ^ (rA & 7);
      int c2 = (kt * 8 + lg + 4) ^ (rA & 7);
      union { bf16x8 v; ull_t q[2]; } u;
      u.q[0] = *(const ull_t*)&s_in[rA * K + c1 * 4];
      u.q[1] = *(const ull_t*)&s_in[rA * K + c2 * 4];
      a[m] = u.v;
    }
#pragma unroll
    for (int n2 = 0; n2 < NTW; ++n2) {
      int nt = wid * NTW + n2;
      bf16x8 b = *(const bf16x8*)&Wp[(((kt * NT + nt) * 64 + lane) * 8)];
#pragma unroll
      for (int m = 0; m < 4; ++m)
        acc[m][n2] = __builtin_amdgcn_mfma_f32_16x16x32_bf16(a[m], b, acc[m][n2], 0, 0, 0);
    }
  }

#pragma unroll
  for (int n2 = 0; n2 < NTW; ++n2) {
    int col = (wid * NTW + n2) * 16 + lr;
    float bv = 0.f;
    if (RELUBIAS) bv = bias[col];
#pragma unroll
    for (int m = 0; m < 4; ++m) {
#pragma unroll
      for (int r = 0; r < 4; ++r) {
        int grow = r0 + m * 16 + lg * 4 + r;
        if (grow < nrows) {
          float v = acc[m][n2][r];
          if (RELUBIAS) v = fmaxf(v + bv, 0.f);
          if constexpr (OUTBF16) {
            ((ushort_t*)outv)[(size_t)grow * out_stride + col] = f2bf(v);
          } else {
            ((float*)outv)[(size_t)grow * out_stride + col] = v;
          }
        }
      }
    }
  }
}

// Fused launch: blocks [0,nbE) run 128-edge EdgeConv tiles (R12 structure);
// blocks [nbE, nbE+nbG) run conv1's CSR gather (8 nodes/block, bf16 in).
// The gather work rides inside edgeconv's latency slack.
__global__ __launch_bounds__(512, 4) void k_fused(
    const float* __restrict__ x, const float* __restrict__ ea,
    const int2* __restrict__ sc_s, const int* __restrict__ dst_s,
    const int* __restrict__ perm_s,
    const unsigned short* __restrict__ W1p, const float* __restrict__ b1,
    const unsigned short* __restrict__ W2p, const float* __restrict__ b2,
    float* __restrict__ h2, int E, int nbE,
    const ushort_t* __restrict__ xb, const int* __restrict__ ptr,
    float* __restrict__ agg1, int n) {
  const int tid = threadIdx.x;
  const int lane = tid & 63, wid = tid >> 6;

  if (blockIdx.x >= nbE) {
    // ---- conv1 gather role: 8 nodes per block, V=1 (64 ch bf16) ----
    const int v = (blockIdx.x - nbE) * 8 + wid;
    if (v >= n) return;
    const int beg = ptr[v], end = ptr[v + 1];
    float acc = 0.f;
    const int cnt = end - beg;
    const int2* scp = sc_s + beg;
    int i = 0;
    for (; i + 4 <= cnt; i += 4) {
      int2 s0 = scp[i], s1 = scp[i + 1], s2 = scp[i + 2], s3 = scp[i + 3];
      float f0 = bf2f(xb[(size_t)s0.x * 64 + lane]);
      float f1 = bf2f(xb[(size_t)s1.x * 64 + lane]);
      float f2 = bf2f(xb[(size_t)s2.x * 64 + lane]);
      float f3 = bf2f(xb[(size_t)s3.x * 64 + lane]);
      acc += f0 * __int_as_float(s0.y) + f1 * __int_as_float(s1.y) +
             f2 * __int_as_float(s2.y) + f3 * __int_as_float(s3.y);
    }
    for (; i < cnt; ++i) {
      int2 s0 = scp[i];
      acc += bf2f(xb[(size_t)s0.x * 64 + lane]) * __int_as_float(s0.y);
    }
    agg1[(size_t)v * 64 + lane] = acc;
    return;
  }

  // ---- EdgeConv role (identical to R12) ----
  __shared__ unsigned short s_buf[256 * 136];  // 69632 B, phase-aliased
  __shared__ int s_src[128], s_dst[128], s_perm[128];
  __shared__ ull_t s_mask[2];
  const int e0 = blockIdx.x * 128;
  if (tid < 128) {
    int e = e0 + tid;
    s_src[tid] = (e < E) ? sc_s[e].x : 0;
    s_dst[tid] = (e < E) ? dst_s[e] : 0;
    s_perm[tid] = (e < E) ? perm_s[e] : 0;
  }
  __syncthreads();
  if (wid < 2) {
    int r = wid * 64 + lane;
    bool chg = (r > 0) && (s_dst[r] != s_dst[r - 1]);
    ull_t m = __ballot(chg);
    if (lane == 0) s_mask[wid] = m;
  }
  // Stage [x_dst | x_src | ea] bf16 into s_buf[row][192], chunk-swizzled.
#pragma unroll
  for (int seg = 0; seg < 3; ++seg) {
#pragma unroll
    for (int it = 0; it < 4; ++it) {
      int idx = it * 512 + tid;   // 0..2047
      int ei = idx >> 4;          // 0..127
      int q = idx & 15;
      const float* row;
      if (seg == 0) row = x + (unsigned)s_dst[ei] * 64u;
      else if (seg == 1) row = x + (unsigned)s_src[ei] * 64u;
      else row = ea + (unsigned)s_perm[ei] * 64u;
      float4 v = make_float4(0.f, 0.f, 0.f, 0.f);
      if (e0 + ei < E) v = *(const float4*)(row + q * 4);
      ushort4 b;
      b.x = f2bf(v.x); b.y = f2bf(v.y); b.z = f2bf(v.z); b.w = f2bf(v.w);
      int chunk = (seg * 16 + q) ^ (ei & 7);
      *(ushort4*)&s_buf[ei * 192 + chunk * 4] = b;
    }
  }
  __syncthreads();

  const int wr = wid >> 2;   // 0..1 : row block (64 rows)
  const int wc = wid & 3;    // 0..3 : col block (64 cols)
  const int lr = lane & 15, lg = lane >> 4;
  f32x4 acc[4][4];
#pragma unroll
  for (int m = 0; m < 4; ++m)
#pragma unroll
    for (int n2 = 0; n2 < 4; ++n2) acc[m][n2] = zero4();

  // GEMM1: K=192 -> hidden 256
#pragma unroll
  for (int kt = 0; kt < 6; ++kt) {
    bf16x8 a[4];
#pragma unroll
    for (int m = 0; m < 4; ++m) {
      int rA = wr * 64 + m * 16 + lr;
      int rr = rA & 7;
      union { bf16x8 v; ull_t q[2]; } u;
      u.q[0] = *(const ull_t*)&s_buf[rA * 192 + ((kt * 8 + lg) ^ rr) * 4];
      u.q[1] = *(const ull_t*)&s_buf[rA * 192 + ((kt * 8 + lg + 4) ^ rr) * 4];
      a[m] = u.v;
    }
#pragma unroll
    for (int n2 = 0; n2 < 4; ++n2) {
      int nt = wc * 4 + n2;
      bf16x8 b = *(const bf16x8*)&W1p[(((kt * 16 + nt) * 64 + lane) * 8)];
#pragma unroll
      for (int m = 0; m < 4; ++m)
        acc[m][n2] = __builtin_amdgcn_mfma_f32_16x16x32_bf16(a[m], b, acc[m][n2], 0, 0, 0);
    }
  }
  __syncthreads();

  // hid = relu(acc1 + b1) bf16 -> s_buf[row][256] COL-PERMUTED, b64 writes.
  {
    float b1v[4];
#pragma unroll
    for (int n2 = 0; n2 < 4; ++n2) b1v[n2] = b1[(wc * 4 + n2) * 16 + lr];
#pragma unroll
    for (int m = 0; m < 4; ++m) {
#pragma unroll
      for (int r = 0; r < 4; ++r) {
        int row = wr * 64 + m * 16 + lg * 4 + r;
        union { ushort_t h[4]; ull_t q; } pk;
        pk.h[0] = f2bf(fmaxf(acc[m][0][r] + b1v[0], 0.f));
        pk.h[1] = f2bf(fmaxf(acc[m][1][r] + b1v[1], 0.f));
        pk.h[2] = f2bf(fmaxf(acc[m][2][r] + b1v[2], 0.f));
        pk.h[3] = f2bf(fmaxf(acc[m][3][r] + b1v[3], 0.f));
        int chunk = (wc * 16 + lr) ^ (row & 7);
        *(ull_t*)&s_buf[row * 256 + chunk * 4] = pk.q;
      }
    }
  }
  __syncthreads();

  // GEMM2: K=256 (permuted k-space; W2p pack PERMK-compensates)
#pragma unroll
  for (int m = 0; m < 4; ++m)
#pragma unroll
    for (int n2 = 0; n2 < 4; ++n2) acc[m][n2] = zero4();
#pragma unroll
  for (int kt = 0; kt < 8; ++kt) {
    bf16x8 a[4];
#pragma unroll
    for (int m = 0; m < 4; ++m) {
      int rA = wr * 64 + m * 16 + lr;
      int rr = rA & 7;
      union { bf16x8 v; ull_t q[2]; } u;
      u.q[0] = *(const ull_t*)&s_buf[rA * 256 + ((kt * 8 + lg) ^ rr) * 4];
      u.q[1] = *(const ull_t*)&s_buf[rA * 256 + ((kt * 8 + lg + 4) ^ rr) * 4];
      a[m] = u.v;
    }
#pragma unroll
    for (int n2 = 0; n2 < 4; ++n2) {
      int nt = wc * 4 + n2;
      bf16x8 b = *(const bf16x8*)&W2p[(((kt * 16 + nt) * 64 + lane) * 8)];
#pragma unroll
      for (int m = 0; m < 4; ++m)
        acc[m][n2] = __builtin_amdgcn_mfma_f32_16x16x32_bf16(a[m], b, acc[m][n2], 0, 0, 0);
    }
  }
  __syncthreads();

  // m = relu(acc2 + b2) -> TRANSPOSED [col][136] as packed b64 (4 rows/write)
#pragma unroll
  for (int n2 = 0; n2 < 4; ++n2) {
    int col = (wc * 4 + n2) * 16 + lr;
    float bv = b2[col];
#pragma unroll
    for (int m = 0; m < 4; ++m) {
      int rbase = wr * 64 + m * 16 + lg * 4;
      union { ushort_t h[4]; ull_t q; } pk;
#pragma unroll
      for (int r = 0; r < 4; ++r) {
        int row = rbase + r;
        float v = (e0 + row < E) ? fmaxf(acc[m][n2][r] + bv, 0.f) : 0.f;
        pk.h[r] = f2bf(v);
      }
      *(ull_t*)&s_buf[col * 136 + rbase] = pk.q;
    }
  }
  __syncthreads();

  // Segmented max scan in u16 domain: thread = (row-half, column), 64 rows each.
  {
    const int col = tid & 255;
    const int half = tid >> 8;       // 0: rows 0..63, 1: rows 64..127
    const int rbeg = half * 64;
    const ull_t mask = s_mask[half];
    unsigned int run = 0;
    int segstart = rbeg;
#pragma unroll
    for (int i = 0; i < 8; ++i) {
      u16x8 pack = *(const u16x8*)&s_buf[col * 136 + rbeg + i * 8];
#pragma unroll
      for (int r2 = 0; r2 < 8; ++r2) {
        int rloc = i * 8 + r2;
        if ((mask >> rloc) & 1ull) {
          if (run > 0)
            atomicMax((int*)h2 + ((unsigned)s_dst[segstart] * 512u + 256u + col),
                      (int)(run << 16));
          run = 0;
          segstart = rbeg + rloc;
        }
        run = max(run, (unsigned int)pack[r2]);
      }
    }
    if (run > 0)
      atomicMax((int*)h2 + ((unsigned)s_dst[segstart] * 512u + 256u + col),
                (int)(run << 16));
  }
}

// Head MLP: wave-per-node, weights (except W2) staged in LDS.
__global__ __launch_bounds__(256) void k_head(
    const float* __restrict__ x, const float* __restrict__ out3,
    const float* __restrict__ W1, const float* __restrict__ b1,
    const float* __restrict__ W2, const float* __restrict__ b2,
    const float* __restrict__ W3, const float* __restrict__ b3,
    const float* __restrict__ W4, const float* __restrict__ b4,
    float* __restrict__ out, int n) {
  __shared__ float sW1[128 * 64];
  __shared__ float sW3[128 * 32];
  __shared__ float sW4[32 * 2];
  __shared__ float sb1[64], sb2[128], sb3[32], sb4[2];
  __shared__ float sbuf[4][352];
  const int tid = threadIdx.x;
  for (int i = tid; i < 128 * 64; i += 256) sW1[i] = W1[i];
  for (int i = tid; i < 128 * 32; i += 256) sW3[i] = W3[i];
  if (tid < 64) sW4[tid] = W4[tid];
  if (tid < 64) sb1[tid] = b1[tid];
  if (tid < 128) sb2[tid] = b2[tid];
  if (tid < 32) sb3[tid] = b3[tid];
  if (tid < 2) sb4[tid] = b4[tid];
  __syncthreads();
  const int wid = tid >> 6, lane = tid & 63;
  float* B = sbuf[wid];
  const int per = gridDim.x * 4;
  const int iters = (n + per - 1) / per;
  for (int it = 0; it < iters; ++it) {
    const int node = it * per + blockIdx.x * 4 + wid;
    const bool act = node < n;
    if (act) {
      B[lane] = x[(size_t)node * 64 + lane];
      B[64 + lane] = out3[(size_t)node * 64 + lane];
    }
    __syncthreads();
    if (act) {
      float o = sb1[lane];
#pragma unroll 8
      for (int k = 0; k < 128; ++k) o += B[k] * sW1[k * 64 + lane];
      B[128 + lane] = softplusf(o);
    }
    __syncthreads();
    if (act) {
      float o0 = sb2[lane], o1 = sb2[64 + lane];
#pragma unroll 8
      for (int k = 0; k < 64; ++k) {
        float v = B[128 + k];
        o0 += v * W2[k * 128 + lane];
        o1 += v * W2[k * 128 + 64 + lane];
      }
      B[192 + lane] = softplusf(o0);
      B[256 + lane] = softplusf(o1);
    }
    __syncthreads();
    if (act && lane < 32) {
      float o = sb3[lane];
#pragma unroll 8
      for (int k = 0; k < 128; ++k) o += B[192 + k] * sW3[k * 32 + lane];
      B[320 + lane] = softplusf(o);
    }
    __syncthreads();
    if (act && lane < 2) {
      float o = sb4[lane];
#pragma unroll
      for (int k = 0; k < 32; ++k) o += B[320 + k] * sW4[k * 2 + lane];
      out[(size_t)lane * n + node] = o;
    }
    __syncthreads();
  }
}

static inline size_t alignup(size_t v) { return (v + 255) & ~(size_t)255; }

extern "C" void kernel_launch(void* const* d_in, const int* in_sizes, int n_in,
                              void* d_out, int out_size, void* d_ws, size_t ws_size,
                              hipStream_t stream) {
  const float* x = (const float*)d_in[0];
  const int* ei = (const int*)d_in[1];
  const float* ea = (const float*)d_in[2];
  const float* c1W = (const float*)d_in[3];
  const float* c1b = (const float*)d_in[4];
  const float* eW1 = (const float*)d_in[5];
  const float* eb1 = (const float*)d_in[6];
  const float* eW2 = (const float*)d_in[7];
  const float* eb2 = (const float*)d_in[8];
  const float* c2W = (const float*)d_in[9];
  const float* c2b = (const float*)d_in[10];
  const float* c3W = (const float*)d_in[11];
  const float* c3b = (const float*)d_in[12];
  const float* l1W = (const float*)d_in[13];
  const float* l1b = (const float*)d_in[14];
  const float* l2W = (const float*)d_in[15];
  const float* l2b = (const float*)d_in[16];
  const float* l3W = (const float*)d_in[17];
  const float* l3b = (const float*)d_in[18];
  const float* l4W = (const float*)d_in[19];
  const float* l4b = (const float*)d_in[20];
  const int n = in_sizes[0] / 64;
  const int E = in_sizes[1] / 2;
  const int* srcs = ei;
  const int* dsts = ei + E;

  char* w = (char*)d_ws;
  auto alloc = [&](size_t bytes) {
    char* p = w;
    w += alignup(bytes);
    return p;
  };
  float* dis = (float*)alloc((size_t)n * 4);
  int* degi = (int*)alloc((size_t)n * 4);
  int* ptr = (int*)alloc((size_t)(n + 1) * 4);
  int* fillc = (int*)alloc((size_t)n * 4);
  int2* sc_s = (int2*)alloc((size_t)E * 8);
  int* dst_s = (int*)alloc((size_t)E * 4);
  int* perm_s = (int*)alloc((size_t)E * 4);
  float* agg1 = (float*)alloc((size_t)n * 64 * 4);
  float* h2 = (float*)alloc((size_t)n * 512 * 4);          // [out1 | out_e1] f32
  ushort_t* hw2b = (ushort_t*)alloc((size_t)n * 256 * 2);  // bf16
  float* out2 = (float*)alloc((size_t)n * 256 * 4);
  ushort_t* hw3b = (ushort_t*)alloc((size_t)n * 64 * 2);   // bf16
  float* out3 = (float*)alloc((size_t)n * 64 * 4);
  ushort_t* xb = (ushort_t*)alloc((size_t)n * 64 * 2);     // x as bf16
  unsigned short* p_c1 = (unsigned short*)alloc(64 * 256 * 2);
  unsigned short* p_e1 = (unsigned short*)alloc(192 * 256 * 2);
  unsigned short* p_e2 = (unsigned short*)alloc(256 * 256 * 2);  // PERMK
  unsigned short* p_c2 = (unsigned short*)alloc(512 * 256 * 2);
  unsigned short* p_c3 = (unsigned short*)alloc(256 * 64 * 2);

  hipMemsetAsync(degi, 0, (size_t)n * 4, stream);
  hipMemsetAsync(fillc, 0, (size_t)n * 4, stream);
  hipMemsetAsync(h2, 0, (size_t)n * 512 * 4, stream);

  // Fused prologue: packs + cvt + deg
  const int n4 = n * 16;
  const int nb_cvt = (n4 + 255) / 256;
  const int nb_deg = (E + 255) / 256;
  k_prologue<<<1088 + nb_cvt + nb_deg, 256, 0, stream>>>(
      c1W, p_c1, eW1, p_e1, eW2, p_e2, c2W, p_c2, c3W, p_c3,
      x, xb, dsts, degi, n4, E, nb_cvt);

  k_scan_dis<<<1, 1024, 0, stream>>>(degi, ptr, dis, n);
  k_fill<<<(E + 255) / 256, 256, 0, stream>>>(srcs, dsts, ptr, dis, fillc,
                                              sc_s, dst_s, perm_s, E);

  const int ablocks = (n + 3) / 4;
  const int gblocks = (n + 63) / 64;
  const int nbE = (E + 127) / 128;
  const int nbG = (n + 7) / 8;

  // Fused: EdgeConv (writes h2[:,256:512]) + conv1 gather (writes agg1)
  k_fused<<<nbE + nbG, 512, 0, stream>>>(x, ea, sc_s, dst_s, perm_s,
                                         p_e1, eb1, p_e2, eb2, h2, E, nbE,
                                         xb, ptr, agg1, n);

  // conv1 GEMM (writes h2[:,0:256]; disjoint columns from edgeconv's atomicMax)
  gcn_gemm<64, 256, true, true, false><<<gblocks, 256, 0, stream>>>(
      agg1, x, dis, p_c1, c1b, h2, 512, n);

  // conv2: matmul (bf16 out) then gather-aggregate (256 ch bf16) + fused finalize
  gcn_gemm<512, 256, false, false, true><<<gblocks, 256, 0, stream>>>(
      h2, nullptr, nullptr, p_c2, nullptr, hw2b, 256, n);
  k_gather_agg<256, true, true><<<ablocks, 256, 0, stream>>>(
      hw2b, sc_s, ptr, dis, hw2b, c2b, out2, n);

  // conv3: matmul (bf16 out) then gather-aggregate (64 ch bf16) + fused finalize
  gcn_gemm<256, 64, false, false, true><<<gblocks, 256, 0, stream>>>(
      out2, nullptr, nullptr, p_c3, nullptr, hw3b, 64, n);
  k_gather_agg<64, true, true><<<ablocks, 256, 0, stream>>>(
      hw3b, sc_s, ptr, dis, hw3b, c3b, out3, n);

  k_head<<<1250, 256, 0, stream>>>(x, out3, l1W, l1b, l2W, l2b, l3W, l3b, l4W, l4b,
                                   (float*)d_out, n);
}

// Round 14
// 591.344 us; speedup vs baseline: 1.0438x; 1.0438x over previous
//
#include <hip/hip_runtime.h>
#include <stdint.h>

typedef __bf16 bf16x8 __attribute__((ext_vector_type(8)));
typedef float f32x4 __attribute__((ext_vector_type(4)));
typedef unsigned short u16x8 __attribute__((ext_vector_type(8)));
typedef unsigned long long ull_t;
typedef unsigned short ushort_t;

#define DEV __device__ __forceinline__

DEV unsigned short f2bf(float f) {
  __bf16 b = (__bf16)f;
  return __builtin_bit_cast(unsigned short, b);
}

DEV float bf2f(unsigned short b) { return __uint_as_float((unsigned int)b << 16); }

DEV f32x4 zero4() { f32x4 z = {0.f, 0.f, 0.f, 0.f}; return z; }

DEV float softplusf(float v) { return (v > 15.f) ? v : log1pf(expf(v)); }

// Pack W[K][Ncols] (f32 row-major) -> fragment-major bf16 (split-4 k-layout).
DEV void pack_dev(const float* __restrict__ W, unsigned short* __restrict__ P,
                  int Ncols, int permk, int idx) {
  int j = idx & 7;
  int lane = (idx >> 3) & 63;
  int rest = idx >> 9;
  int NT = Ncols >> 4;
  int nt = rest % NT;
  int kt = rest / NT;
  int k = kt * 32 + ((j >> 2) * 16) + ((lane >> 4) * 4) + (j & 3);
  if (permk) k = (k & ~63) | ((k & 3) << 4) | ((k >> 2) & 15);
  int col = nt * 16 + (lane & 15);
  P[idx] = f2bf(W[(size_t)k * Ncols + col]);
}

// Fused prologue: 5 weight packs + x->bf16 cvt + degree count, role-split by block.
__global__ __launch_bounds__(256) void k_prologue(
    const float* __restrict__ c1W, unsigned short* __restrict__ p_c1,
    const float* __restrict__ eW1, unsigned short* __restrict__ p_e1,
    const float* __restrict__ eW2, unsigned short* __restrict__ p_e2,
    const float* __restrict__ c2W, unsigned short* __restrict__ p_c2,
    const float* __restrict__ c3W, unsigned short* __restrict__ p_c3,
    const float* __restrict__ x, ushort_t* __restrict__ xb,
    const int* __restrict__ dsts, int* __restrict__ degi,
    int n4, int E, int nb_cvt) {
  const int b = blockIdx.x;
  const int tid = threadIdx.x;
  if (b < 64) {
    pack_dev(c1W, p_c1, 256, 0, b * 256 + tid);
  } else if (b < 256) {
    pack_dev(eW1, p_e1, 256, 0, (b - 64) * 256 + tid);
  } else if (b < 512) {
    pack_dev(eW2, p_e2, 256, 1, (b - 256) * 256 + tid);
  } else if (b < 1024) {
    pack_dev(c2W, p_c2, 256, 0, (b - 512) * 256 + tid);
  } else if (b < 1088) {
    pack_dev(c3W, p_c3, 64, 0, (b - 1024) * 256 + tid);
  } else if (b < 1088 + nb_cvt) {
    int i = (b - 1088) * 256 + tid;
    if (i < n4) {
      float4 v = *(const float4*)(x + (size_t)i * 4);
      ushort4 u;
      u.x = f2bf(v.x); u.y = f2bf(v.y); u.z = f2bf(v.z); u.w = f2bf(v.w);
      *(ushort4*)(xb + (size_t)i * 4) = u;
    }
  } else {
    int i = (b - 1088 - nb_cvt) * 256 + tid;
    if (i < E) atomicAdd(&degi[dsts[i]], 1);
  }
}

// Single-block exclusive scan + dis = rsqrt(deg+1).
__global__ __launch_bounds__(1024) void k_scan_dis(const int* __restrict__ degi,
                                                   int* __restrict__ ptr,
                                                   float* __restrict__ dis, int n) {
  __shared__ int part[1024];
  const int tid = threadIdx.x;
  const int chunk = (n + 1023) / 1024;
  const int b = tid * chunk;
  const int e2 = min(n, b + chunk);
  int s = 0;
  for (int i = b; i < e2; ++i) {
    int d = degi[i];
    dis[i] = rsqrtf((float)d + 1.0f);
    s += d;
  }
  part[tid] = s;
  __syncthreads();
  for (int off = 1; off < 1024; off <<= 1) {
    int val = (tid >= off) ? part[tid - off] : 0;
    __syncthreads();
    part[tid] += val;
    __syncthreads();
  }
  int run = (tid == 0) ? 0 : part[tid - 1];
  for (int i = b; i < e2; ++i) {
    ptr[i] = run;
    run += degi[i];
  }
  if (tid == 1023) ptr[n] = run;
}

// Counting-sort fill: edges grouped by dst; store (src, dis[src]*dis[dst]).
__global__ void k_fill(const int* __restrict__ srcs, const int* __restrict__ dsts,
                       const int* __restrict__ ptr, const float* __restrict__ dis,
                       int* __restrict__ fillc,
                       int2* __restrict__ sc_s, int* __restrict__ dst_s,
                       int* __restrict__ perm_s, int E) {
  int e = blockIdx.x * 256 + threadIdx.x;
  if (e >= E) return;
  int d = dsts[e];
  int s = srcs[e];
  int pos = ptr[d] + atomicAdd(&fillc[d], 1);
  float c = dis[s] * dis[d];
  sc_s[pos] = make_int2(s, __float_as_int(c));
  dst_s[pos] = d;
  perm_s[pos] = e;
}

// Per-node CSR gather: acc = sum_{e in N(v)} feat[src_e]*c_e, 4-deep unrolled.
template <int COLS, bool FINALIZE, bool INBF16>
__global__ __launch_bounds__(256) void k_gather_agg(
    const void* __restrict__ featv, const int2* __restrict__ sc,
    const int* __restrict__ ptr, const float* __restrict__ dis,
    const void* __restrict__ hwv, const float* __restrict__ bias,
    float* __restrict__ out, int n) {
  constexpr int V = COLS / 64;
  const int v = blockIdx.x * 4 + (threadIdx.x >> 6);
  if (v >= n) return;
  const int lane = threadIdx.x & 63;
  const int beg = ptr[v], end = ptr[v + 1];

  auto loadrow = [&](int s, float* f) {
    if constexpr (INBF16) {
      const ushort_t* feat = (const ushort_t*)featv;
      if constexpr (V == 4) {
        ushort4 u = *(const ushort4*)(feat + (size_t)s * COLS + lane * 4);
        f[0] = bf2f(u.x); f[1] = bf2f(u.y); f[2] = bf2f(u.z); f[3] = bf2f(u.w);
      } else {
        f[0] = bf2f(feat[(size_t)s * COLS + lane]);
      }
    } else {
      const float* feat = (const float*)featv;
      if constexpr (V == 4) {
        float4 q = *(const float4*)(feat + (size_t)s * COLS + lane * 4);
        f[0] = q.x; f[1] = q.y; f[2] = q.z; f[3] = q.w;
      } else {
        f[0] = feat[(size_t)s * COLS + lane];
      }
    }
  };

  float acc[V];
#pragma unroll
  for (int i = 0; i < V; ++i) acc[i] = 0.f;
  const int cnt = end - beg;
  const int2* scp = sc + beg;
  int i = 0;
  for (; i + 4 <= cnt; i += 4) {
    int2 s0 = scp[i], s1 = scp[i + 1], s2 = scp[i + 2], s3 = scp[i + 3];
    float f0[V], f1[V], f2[V], f3[V];
    loadrow(s0.x, f0); loadrow(s1.x, f1); loadrow(s2.x, f2); loadrow(s3.x, f3);
    float c0 = __int_as_float(s0.y), c1 = __int_as_float(s1.y);
    float c2 = __int_as_float(s2.y), c3 = __int_as_float(s3.y);
#pragma unroll
    for (int j = 0; j < V; ++j)
      acc[j] += f0[j] * c0 + f1[j] * c1 + f2[j] * c2 + f3[j] * c3;
  }
  for (; i < cnt; ++i) {
    int2 s0 = scp[i];
    float c0 = __int_as_float(s0.y);
    float f0[V];
    loadrow(s0.x, f0);
#pragma unroll
    for (int j = 0; j < V; ++j) acc[j] += f0[j] * c0;
  }
  float* op = out + (size_t)v * COLS + lane * V;
  if constexpr (FINALIZE) {
    const float dv = dis[v];
    float d2 = dv * dv;
    float h[V];
    if constexpr (INBF16) {
      const ushort_t* hw = (const ushort_t*)hwv;
      if constexpr (V == 4) {
        ushort4 u = *(const ushort4*)(hw + (size_t)v * COLS + lane * 4);
        h[0] = bf2f(u.x); h[1] = bf2f(u.y); h[2] = bf2f(u.z); h[3] = bf2f(u.w);
      } else {
        h[0] = bf2f(hw[(size_t)v * COLS + lane]);
      }
    } else {
      const float* hw = (const float*)hwv;
      if constexpr (V == 4) {
        float4 q = *(const float4*)(hw + (size_t)v * COLS + lane * 4);
        h[0] = q.x; h[1] = q.y; h[2] = q.z; h[3] = q.w;
      } else {
        h[0] = hw[(size_t)v * COLS + lane];
      }
    }
#pragma unroll
    for (int i2 = 0; i2 < V; ++i2)
      acc[i2] = fmaxf(acc[i2] + h[i2] * d2 + bias[lane * V + i2], 0.f);
  }
  if constexpr (V == 4) {
    *(float4*)op = make_float4(acc[0], acc[1], acc[2], acc[3]);
  } else {
    op[0] = acc[0];
  }
}

// Generic node GEMM: out[r,:NOUT] = inA[r,:K] (+inB[r,:K]*dis[r]^2) @ Wp (+bias, relu)
template <int K, int NOUT, bool COMPOSE, bool RELUBIAS, bool OUTBF16>
__global__ __launch_bounds__(256, 2) void gcn_gemm(
    const float* __restrict__ inA, const float* __restrict__ inB,
    const float* __restrict__ dis,
    const unsigned short* __restrict__ Wp, const float* __restrict__ bias,
    void* __restrict__ outv, int out_stride, int nrows) {
  constexpr int NT = NOUT / 16;
  constexpr int NTW = NOUT / 64;
  __shared__ unsigned short s_in[64 * K];
  const int tid = threadIdx.x;
  const int r0 = blockIdx.x * 64;

  constexpr int C4R = K / 4;
  for (int idx = tid; idx < 64 * C4R; idx += 256) {
    int row = idx / C4R;
    int rem = idx - row * C4R;
    int grow = r0 + row;
    float4 v = make_float4(0.f, 0.f, 0.f, 0.f);
    if (grow < nrows) {
      v = *(const float4*)&inA[(size_t)grow * K + rem * 4];
      if constexpr (COMPOSE) {
        float d = dis[grow];
        d *= d;
        float4 w2 = *(const float4*)&inB[(size_t)grow * K + rem * 4];
        v.x += w2.x * d; v.y += w2.y * d; v.z += w2.z * d; v.w += w2.w * d;
      }
    }
    ushort4 b;
    b.x = f2bf(v.x); b.y = f2bf(v.y); b.z = f2bf(v.z); b.w = f2bf(v.w);
    *(ushort4*)&s_in[row * K + ((rem ^ (row & 7)) * 4)] = b;
  }
  __syncthreads();

  const int lane = tid & 63, wid = tid >> 6;
  const int lr = lane & 15, lg = lane >> 4;
  f32x4 acc[4][NTW];
#pragma unroll
  for (int m = 0; m < 4; ++m)
#pragma unroll
    for (int n2 = 0; n2 < NTW; ++n2) acc[m][n2] = zero4();

#pragma unroll
  for (int kt = 0; kt < K / 32; ++kt) {
    bf16x8 a[4];
#pragma unroll
    for (int m = 0; m < 4; ++m) {
      int rA = m * 16 + lr;
      int c1 = (kt * 8 + lg) ^ (rA & 7);
      int c2 = (kt * 8 + lg + 4) ^ (rA & 7);
      union { bf16x8 v; ull_t q[2]; } u;
      u.q[0] = *(const ull_t*)&s_in[rA * K + c1 * 4];
      u.q[1] = *(const ull_t*)&s_in[rA * K + c2 * 4];
      a[m] = u.v;
    }
#pragma unroll
    for (int n2 = 0; n2 < NTW; ++n2) {
      int nt = wid * NTW + n2;
      bf16x8 b = *(const bf16x8*)&Wp[(((kt * NT + nt) * 64 + lane) * 8)];
#pragma unroll
      for (int m = 0; m < 4; ++m)
        acc[m][n2] = __builtin_amdgcn_mfma_f32_16x16x32_bf16(a[m], b, acc[m][n2], 0, 0, 0);
    }
  }

#pragma unroll
  for (int n2 = 0; n2 < NTW; ++n2) {
    int col = (wid * NTW + n2) * 16 + lr;
    float bv = 0.f;
    if (RELUBIAS) bv = bias[col];
#pragma unroll
    for (int m = 0; m < 4; ++m) {
#pragma unroll
      for (int r = 0; r < 4; ++r) {
        int grow = r0 + m * 16 + lg * 4 + r;
        if (grow < nrows) {
          float v = acc[m][n2][r];
          if (RELUBIAS) v = fmaxf(v + bv, 0.f);
          if constexpr (OUTBF16) {
            ((ushort_t*)outv)[(size_t)grow * out_stride + col] = f2bf(v);
          } else {
            ((float*)outv)[(size_t)grow * out_stride + col] = v;
          }
        }
      }
    }
  }
}

// conv2 GEMM: K=512 where cols 0-255 come from h2a (bf16, raw copy) and
// cols 256-511 from h2b (f32, cvt). Out bf16 (hw2b).
__global__ __launch_bounds__(256, 2) void gcn_gemm_mix(
    const ushort_t* __restrict__ h2a, const float* __restrict__ h2b,
    const unsigned short* __restrict__ Wp, ushort_t* __restrict__ outv,
    int nrows) {
  constexpr int K = 512, NT = 16, NTW = 4;
  __shared__ unsigned short s_in[64 * K];
  const int tid = threadIdx.x;
  const int r0 = blockIdx.x * 64;

  for (int idx = tid; idx < 64 * 128; idx += 256) {
    int row = idx >> 7;
    int rem = idx & 127;
    int grow = r0 + row;
    ushort4 b = make_ushort4(0, 0, 0, 0);
    if (grow < nrows) {
      if (rem < 64) {
        b = *(const ushort4*)&h2a[(size_t)grow * 256 + rem * 4];
      } else {
        float4 v = *(const float4*)&h2b[(size_t)grow * 256 + (rem - 64) * 4];
        b.x = f2bf(v.x); b.y = f2bf(v.y); b.z = f2bf(v.z); b.w = f2bf(v.w);
      }
    }
    *(ushort4*)&s_in[row * K + ((rem ^ (row & 7)) * 4)] = b;
  }
  __syncthreads();

  const int lane = tid & 63, wid = tid >> 6;
  const int lr = lane & 15, lg = lane >> 4;
  f32x4 acc[4][NTW];
#pragma unroll
  for (int m = 0; m < 4; ++m)
#pragma unroll
    for (int n2 = 0; n2 < NTW; ++n2) acc[m][n2] = zero4();

#pragma unroll
  for (int kt = 0; kt < K / 32; ++kt) {
    bf16x8 a[4];
#pragma unroll
    for (int m = 0; m < 4; ++m) {
      int rA = m * 16 + lr;
      int c1 = (kt * 8 + lg) ^ (rA & 7);
      int c2 = (kt * 8 + lg + 4) ^ (rA & 7);
      union { bf16x8 v; ull_t q[2]; } u;
      u.q[0] = *(const ull_t*)&s_in[rA * K + c1 * 4];
      u.q[1] = *(const ull_t*)&s_in[rA * K + c2 * 4];
      a[m] = u.v;
    }
#pragma unroll
    for (int n2 = 0; n2 < NTW; ++n2) {
      int nt = wid * NTW + n2;
      bf16x8 b = *(const bf16x8*)&Wp[(((kt * NT + nt) * 64 + lane) * 8)];
#pragma unroll
      for (int m = 0; m < 4; ++m)
        acc[m][n2] = __builtin_amdgcn_mfma_f32_16x16x32_bf16(a[m], b, acc[m][n2], 0, 0, 0);
    }
  }

#pragma unroll
  for (int n2 = 0; n2 < NTW; ++n2) {
    int col = (wid * NTW + n2) * 16 + lr;
#pragma unroll
    for (int m = 0; m < 4; ++m) {
#pragma unroll
      for (int r = 0; r < 4; ++r) {
        int grow = r0 + m * 16 + lg * 4 + r;
        if (grow < nrows)
          outv[(size_t)grow * 256 + col] = f2bf(acc[m][n2][r]);
      }
    }
  }
}

// Fused EdgeConv on dst-sorted edges. 128-edge tiles (R12 structure).
// atomicMax targets h2b[n][256] (f32, zero-init).
__global__ __launch_bounds__(512, 4) void k_edgeconv(
    const float* __restrict__ x, const float* __restrict__ ea,
    const int2* __restrict__ sc_s, const int* __restrict__ dst_s,
    const int* __restrict__ perm_s,
    const unsigned short* __restrict__ W1p, const float* __restrict__ b1,
    const unsigned short* __restrict__ W2p, const float* __restrict__ b2,
    float* __restrict__ h2b, int E) {
  __shared__ unsigned short s_buf[256 * 136];  // 69632 B, phase-aliased
  __shared__ int s_src[128], s_dst[128], s_perm[128];
  __shared__ ull_t s_mask[2];
  const int tid = threadIdx.x;
  const int e0 = blockIdx.x * 128;
  const int lane = tid & 63, wid = tid >> 6;
  if (tid < 128) {
    int e = e0 + tid;
    s_src[tid] = (e < E) ? sc_s[e].x : 0;
    s_dst[tid] = (e < E) ? dst_s[e] : 0;
    s_perm[tid] = (e < E) ? perm_s[e] : 0;
  }
  __syncthreads();
  if (wid < 2) {
    int r = wid * 64 + lane;
    bool chg = (r > 0) && (s_dst[r] != s_dst[r - 1]);
    ull_t m = __ballot(chg);
    if (lane == 0) s_mask[wid] = m;
  }
#pragma unroll
  for (int seg = 0; seg < 3; ++seg) {
#pragma unroll
    for (int it = 0; it < 4; ++it) {
      int idx = it * 512 + tid;
      int ei = idx >> 4;
      int q = idx & 15;
      const float* row;
      if (seg == 0) row = x + (unsigned)s_dst[ei] * 64u;
      else if (seg == 1) row = x + (unsigned)s_src[ei] * 64u;
      else row = ea + (unsigned)s_perm[ei] * 64u;
      float4 v = make_float4(0.f, 0.f, 0.f, 0.f);
      if (e0 + ei < E) v = *(const float4*)(row + q * 4);
      ushort4 b;
      b.x = f2bf(v.x); b.y = f2bf(v.y); b.z = f2bf(v.z); b.w = f2bf(v.w);
      int chunk = (seg * 16 + q) ^ (ei & 7);
      *(ushort4*)&s_buf[ei * 192 + chunk * 4] = b;
    }
  }
  __syncthreads();

  const int wr = wid >> 2;
  const int wc = wid & 3;
  const int lr = lane & 15, lg = lane >> 4;
  f32x4 acc[4][4];
#pragma unroll
  for (int m = 0; m < 4; ++m)
#pragma unroll
    for (int n2 = 0; n2 < 4; ++n2) acc[m][n2] = zero4();

  // GEMM1: K=192 -> hidden 256
#pragma unroll
  for (int kt = 0; kt < 6; ++kt) {
    bf16x8 a[4];
#pragma unroll
    for (int m = 0; m < 4; ++m) {
      int rA = wr * 64 + m * 16 + lr;
      int rr = rA & 7;
      union { bf16x8 v; ull_t q[2]; } u;
      u.q[0] = *(const ull_t*)&s_buf[rA * 192 + ((kt * 8 + lg) ^ rr) * 4];
      u.q[1] = *(const ull_t*)&s_buf[rA * 192 + ((kt * 8 + lg + 4) ^ rr) * 4];
      a[m] = u.v;
    }
#pragma unroll
    for (int n2 = 0; n2 < 4; ++n2) {
      int nt = wc * 4 + n2;
      bf16x8 b = *(const bf16x8*)&W1p[(((kt * 16 + nt) * 64 + lane) * 8)];
#pragma unroll
      for (int m = 0; m < 4; ++m)
        acc[m][n2] = __builtin_amdgcn_mfma_f32_16x16x32_bf16(a[m], b, acc[m][n2], 0, 0, 0);
    }
  }
  __syncthreads();

  // hid = relu(acc1 + b1) bf16 -> s_buf[row][256] COL-PERMUTED, b64 writes.
  {
    float b1v[4];
#pragma unroll
    for (int n2 = 0; n2 < 4; ++n2) b1v[n2] = b1[(wc * 4 + n2) * 16 + lr];
#pragma unroll
    for (int m = 0; m < 4; ++m) {
#pragma unroll
      for (int r = 0; r < 4; ++r) {
        int row = wr * 64 + m * 16 + lg * 4 + r;
        union { ushort_t h[4]; ull_t q; } pk;
        pk.h[0] = f2bf(fmaxf(acc[m][0][r] + b1v[0], 0.f));
        pk.h[1] = f2bf(fmaxf(acc[m][1][r] + b1v[1], 0.f));
        pk.h[2] = f2bf(fmaxf(acc[m][2][r] + b1v[2], 0.f));
        pk.h[3] = f2bf(fmaxf(acc[m][3][r] + b1v[3], 0.f));
        int chunk = (wc * 16 + lr) ^ (row & 7);
        *(ull_t*)&s_buf[row * 256 + chunk * 4] = pk.q;
      }
    }
  }
  __syncthreads();

  // GEMM2: K=256 (permuted k-space; W2p pack PERMK-compensates)
#pragma unroll
  for (int m = 0; m < 4; ++m)
#pragma unroll
    for (int n2 = 0; n2 < 4; ++n2) acc[m][n2] = zero4();
#pragma unroll
  for (int kt = 0; kt < 8; ++kt) {
    bf16x8 a[4];
#pragma unroll
    for (int m = 0; m < 4; ++m) {
      int rA = wr * 64 + m * 16 + lr;
      int rr = rA & 7;
      union { bf16x8 v; ull_t q[2]; } u;
      u.q[0] = *(const ull_t*)&s_buf[rA * 256 + ((kt * 8 + lg) ^ rr) * 4];
      u.q[1] = *(const ull_t*)&s_buf[rA * 256 + ((kt * 8 + lg + 4) ^ rr) * 4];
      a[m] = u.v;
    }
#pragma unroll
    for (int n2 = 0; n2 < 4; ++n2) {
      int nt = wc * 4 + n2;
      bf16x8 b = *(const bf16x8*)&W2p[(((kt * 16 + nt) * 64 + lane) * 8)];
#pragma unroll
      for (int m = 0; m < 4; ++m)
        acc[m][n2] = __builtin_amdgcn_mfma_f32_16x16x32_bf16(a[m], b, acc[m][n2], 0, 0, 0);
    }
  }
  __syncthreads();

  // m = relu(acc2 + b2) -> TRANSPOSED [col][136] as packed b64
#pragma unroll
  for (int n2 = 0; n2 < 4; ++n2) {
    int col = (wc * 4 + n2) * 16 + lr;
    float bv = b2[col];
#pragma unroll
    for (int m = 0; m < 4; ++m) {
      int rbase = wr * 64 + m * 16 + lg * 4;
      union { ushort_t h[4]; ull_t q; } pk;
#pragma unroll
      for (int r = 0; r < 4; ++r) {
        int row = rbase + r;
        float v = (e0 + row < E) ? fmaxf(acc[m][n2][r] + bv, 0.f) : 0.f;
        pk.h[r] = f2bf(v);
      }
      *(ull_t*)&s_buf[col * 136 + rbase] = pk.q;
    }
  }
  __syncthreads();

  // Segmented max scan in u16 domain.
  {
    const int col = tid & 255;
    const int half = tid >> 8;
    const int rbeg = half * 64;
    const ull_t mask = s_mask[half];
    unsigned int run = 0;
    int segstart = rbeg;
#pragma unroll
    for (int i = 0; i < 8; ++i) {
      u16x8 pack = *(const u16x8*)&s_buf[col * 136 + rbeg + i * 8];
#pragma unroll
      for (int r2 = 0; r2 < 8; ++r2) {
        int rloc = i * 8 + r2;
        if ((mask >> rloc) & 1ull) {
          if (run > 0)
            atomicMax((int*)h2b + ((unsigned)s_dst[segstart] * 256u + col),
                      (int)(run << 16));
          run = 0;
          segstart = rbeg + rloc;
        }
        run = max(run, (unsigned int)pack[r2]);
      }
    }
    if (run > 0)
      atomicMax((int*)h2b + ((unsigned)s_dst[segstart] * 256u + col),
                (int)(run << 16));
  }
}

// Head MLP: wave-per-node, weights (except W2) staged in LDS.
__global__ __launch_bounds__(256) void k_head(
    const float* __restrict__ x, const float* __restrict__ out3,
    const float* __restrict__ W1, const float* __restrict__ b1,
    const float* __restrict__ W2, const float* __restrict__ b2,
    const float* __restrict__ W3, const float* __restrict__ b3,
    const float* __restrict__ W4, const float* __restrict__ b4,
    float* __restrict__ out, int n) {
  __shared__ float sW1[128 * 64];
  __shared__ float sW3[128 * 32];
  __shared__ float sW4[32 * 2];
  __shared__ float sb1[64], sb2[128], sb3[32], sb4[2];
  __shared__ float sbuf[4][352];
  const int tid = threadIdx.x;
  for (int i = tid; i < 128 * 64; i += 256) sW1[i] = W1[i];
  for (int i = tid; i < 128 * 32; i += 256) sW3[i] = W3[i];
  if (tid < 64) sW4[tid] = W4[tid];
  if (tid < 64) sb1[tid] = b1[tid];
  if (tid < 128) sb2[tid] = b2[tid];
  if (tid < 32) sb3[tid] = b3[tid];
  if (tid < 2) sb4[tid] = b4[tid];
  __syncthreads();
  const int wid = tid >> 6, lane = tid & 63;
  float* B = sbuf[wid];
  const int per = gridDim.x * 4;
  const int iters = (n + per - 1) / per;
  for (int it = 0; it < iters; ++it) {
    const int node = it * per + blockIdx.x * 4 + wid;
    const bool act = node < n;
    if (act) {
      B[lane] = x[(size_t)node * 64 + lane];
      B[64 + lane] = out3[(size_t)node * 64 + lane];
    }
    __syncthreads();
    if (act) {
      float o = sb1[lane];
#pragma unroll 8
      for (int k = 0; k < 128; ++k) o += B[k] * sW1[k * 64 + lane];
      B[128 + lane] = softplusf(o);
    }
    __syncthreads();
    if (act) {
      float o0 = sb2[lane], o1 = sb2[64 + lane];
#pragma unroll 8
      for (int k = 0; k < 64; ++k) {
        float v = B[128 + k];
        o0 += v * W2[k * 128 + lane];
        o1 += v * W2[k * 128 + 64 + lane];
      }
      B[192 + lane] = softplusf(o0);
      B[256 + lane] = softplusf(o1);
    }
    __syncthreads();
    if (act && lane < 32) {
      float o = sb3[lane];
#pragma unroll 8
      for (int k = 0; k < 128; ++k) o += B[192 + k] * sW3[k * 32 + lane];
      B[320 + lane] = softplusf(o);
    }
    __syncthreads();
    if (act && lane < 2) {
      float o = sb4[lane];
#pragma unroll
      for (int k = 0; k < 32; ++k) o += B[320 + k] * sW4[k * 2 + lane];
      out[(size_t)lane * n + node] = o;
    }
    __syncthreads();
  }
}

static inline size_t alignup(size_t v) { return (v + 255) & ~(size_t)255; }

extern "C" void kernel_launch(void* const* d_in, const int* in_sizes, int n_in,
                              void* d_out, int out_size, void* d_ws, size_t ws_size,
                              hipStream_t stream) {
  const float* x = (const float*)d_in[0];
  const int* ei = (const int*)d_in[1];
  const float* ea = (const float*)d_in[2];
  const float* c1W = (const float*)d_in[3];
  const float* c1b = (const float*)d_in[4];
  const float* eW1 = (const float*)d_in[5];
  const float* eb1 = (const float*)d_in[6];
  const float* eW2 = (const float*)d_in[7];
  const float* eb2 = (const float*)d_in[8];
  const float* c2W = (const float*)d_in[9];
  const float* c2b = (const float*)d_in[10];
  const float* c3W = (const float*)d_in[11];
  const float* c3b = (const float*)d_in[12];
  const float* l1W = (const float*)d_in[13];
  const float* l1b = (const float*)d_in[14];
  const float* l2W = (const float*)d_in[15];
  const float* l2b = (const float*)d_in[16];
  const float* l3W = (const float*)d_in[17];
  const float* l3b = (const float*)d_in[18];
  const float* l4W = (const float*)d_in[19];
  const float* l4b = (const float*)d_in[20];
  const int n = in_sizes[0] / 64;
  const int E = in_sizes[1] / 2;
  const int* srcs = ei;
  const int* dsts = ei + E;

  char* w = (char*)d_ws;
  auto alloc = [&](size_t bytes) {
    char* p = w;
    w += alignup(bytes);
    return p;
  };
  float* dis = (float*)alloc((size_t)n * 4);
  int* degi = (int*)alloc((size_t)n * 4);
  int* ptr = (int*)alloc((size_t)(n + 1) * 4);
  int* fillc = (int*)alloc((size_t)n * 4);
  int2* sc_s = (int2*)alloc((size_t)E * 8);
  int* dst_s = (int*)alloc((size_t)E * 4);
  int* perm_s = (int*)alloc((size_t)E * 4);
  float* agg1 = (float*)alloc((size_t)n * 64 * 4);
  ushort_t* h2a = (ushort_t*)alloc((size_t)n * 256 * 2);   // conv1 out, bf16
  float* h2b = (float*)alloc((size_t)n * 256 * 4);         // edgeconv max, f32
  ushort_t* hw2b = (ushort_t*)alloc((size_t)n * 256 * 2);  // bf16
  float* out2 = (float*)alloc((size_t)n * 256 * 4);
  ushort_t* hw3b = (ushort_t*)alloc((size_t)n * 64 * 2);   // bf16
  float* out3 = (float*)alloc((size_t)n * 64 * 4);
  ushort_t* xb = (ushort_t*)alloc((size_t)n * 64 * 2);     // x as bf16
  unsigned short* p_c1 = (unsigned short*)alloc(64 * 256 * 2);
  unsigned short* p_e1 = (unsigned short*)alloc(192 * 256 * 2);
  unsigned short* p_e2 = (unsigned short*)alloc(256 * 256 * 2);  // PERMK
  unsigned short* p_c2 = (unsigned short*)alloc(512 * 256 * 2);
  unsigned short* p_c3 = (unsigned short*)alloc(256 * 64 * 2);

  hipMemsetAsync(degi, 0, (size_t)n * 4, stream);
  hipMemsetAsync(fillc, 0, (size_t)n * 4, stream);
  hipMemsetAsync(h2b, 0, (size_t)n * 256 * 4, stream);

  const int n4 = n * 16;
  const int nb_cvt = (n4 + 255) / 256;
  const int nb_deg = (E + 255) / 256;
  k_prologue<<<1088 + nb_cvt + nb_deg, 256, 0, stream>>>(
      c1W, p_c1, eW1, p_e1, eW2, p_e2, c2W, p_c2, c3W, p_c3,
      x, xb, dsts, degi, n4, E, nb_cvt);

  k_scan_dis<<<1, 1024, 0, stream>>>(degi, ptr, dis, n);
  k_fill<<<(E + 255) / 256, 256, 0, stream>>>(srcs, dsts, ptr, dis, fillc,
                                              sc_s, dst_s, perm_s, E);

  const int ablocks = (n + 3) / 4;
  const int gblocks = (n + 63) / 64;

  // conv1: gather-aggregate xb (bf16), then GEMM (bf16 out -> h2a)
  k_gather_agg<64, false, true><<<ablocks, 256, 0, stream>>>(
      xb, sc_s, ptr, dis, nullptr, nullptr, agg1, n);
  gcn_gemm<64, 256, true, true, true><<<gblocks, 256, 0, stream>>>(
      agg1, x, dis, p_c1, c1b, h2a, 256, n);

  // EdgeConv -> h2b (128-edge tiles)
  k_edgeconv<<<(E + 127) / 128, 512, 0, stream>>>(x, ea, sc_s, dst_s, perm_s,
                                                  p_e1, eb1, p_e2, eb2, h2b, E);

  // conv2: mixed-source GEMM (h2a bf16 | h2b f32) -> hw2b, then gather+finalize
  gcn_gemm_mix<<<gblocks, 256, 0, stream>>>(h2a, h2b, p_c2, hw2b, n);
  k_gather_agg<256, true, true><<<ablocks, 256, 0, stream>>>(
      hw2b, sc_s, ptr, dis, hw2b, c2b, out2, n);

  // conv3: matmul (bf16 out) then gather-aggregate + finalize
  gcn_gemm<256, 64, false, false, true><<<gblocks, 256, 0, stream>>>(
      out2, nullptr, nullptr, p_c3, nullptr, hw3b, 64, n);
  k_gather_agg<64, true, true><<<ablocks, 256, 0, stream>>>(
      hw3b, sc_s, ptr, dis, hw3b, c3b, out3, n);

  k_head<<<1250, 256, 0, stream>>>(x, out3, l1W, l1b, l2W, l2b, l3W, l3b, l4W, l4b,
                                   (float*)d_out, n);
}

// Round 15
// 580.489 us; speedup vs baseline: 1.0633x; 1.0187x over previous
//
#include <hip/hip_runtime.h>
#include <stdint.h>

typedef __bf16 bf16x8 __attribute__((ext_vector_type(8)));
typedef float f32x4 __attribute__((ext_vector_type(4)));
typedef unsigned short u16x8 __attribute__((ext_vector_type(8)));
typedef unsigned long long ull_t;
typedef unsigned short ushort_t;

#define DEV __device__ __forceinline__

DEV unsigned short f2bf(float f) {
  __bf16 b = (__bf16)f;
  return __builtin_bit_cast(unsigned short, b);
}

DEV float bf2f(unsigned short b) { return __uint_as_float((unsigned int)b << 16); }

DEV f32x4 zero4() { f32x4 z = {0.f, 0.f, 0.f, 0.f}; return z; }

DEV float softplusf(float v) { return (v > 15.f) ? v : log1pf(expf(v)); }

// Pack W[K][Ncols] (f32 row-major) -> fragment-major bf16 (split-4 k-layout).
DEV void pack_dev(const float* __restrict__ W, unsigned short* __restrict__ P,
                  int Ncols, int permk, int idx) {
  int j = idx & 7;
  int lane = (idx >> 3) & 63;
  int rest = idx >> 9;
  int NT = Ncols >> 4;
  int nt = rest % NT;
  int kt = rest / NT;
  int k = kt * 32 + ((j >> 2) * 16) + ((lane >> 4) * 4) + (j & 3);
  if (permk) k = (k & ~63) | ((k & 3) << 4) | ((k >> 2) & 15);
  int col = nt * 16 + (lane & 15);
  P[idx] = f2bf(W[(size_t)k * Ncols + col]);
}

// Fused prologue: 5 weight packs + x->bf16 cvt + degree count, role-split by block.
__global__ __launch_bounds__(256) void k_prologue(
    const float* __restrict__ c1W, unsigned short* __restrict__ p_c1,
    const float* __restrict__ eW1, unsigned short* __restrict__ p_e1,
    const float* __restrict__ eW2, unsigned short* __restrict__ p_e2,
    const float* __restrict__ c2W, unsigned short* __restrict__ p_c2,
    const float* __restrict__ c3W, unsigned short* __restrict__ p_c3,
    const float* __restrict__ x, ushort_t* __restrict__ xb,
    const int* __restrict__ dsts, int* __restrict__ degi,
    int n4, int E, int nb_cvt) {
  const int b = blockIdx.x;
  const int tid = threadIdx.x;
  if (b < 64) {
    pack_dev(c1W, p_c1, 256, 0, b * 256 + tid);
  } else if (b < 256) {
    pack_dev(eW1, p_e1, 256, 0, (b - 64) * 256 + tid);
  } else if (b < 512) {
    pack_dev(eW2, p_e2, 256, 1, (b - 256) * 256 + tid);
  } else if (b < 1024) {
    pack_dev(c2W, p_c2, 256, 0, (b - 512) * 256 + tid);
  } else if (b < 1088) {
    pack_dev(c3W, p_c3, 64, 0, (b - 1024) * 256 + tid);
  } else if (b < 1088 + nb_cvt) {
    int i = (b - 1088) * 256 + tid;
    if (i < n4) {
      float4 v = *(const float4*)(x + (size_t)i * 4);
      ushort4 u;
      u.x = f2bf(v.x); u.y = f2bf(v.y); u.z = f2bf(v.z); u.w = f2bf(v.w);
      *(ushort4*)(xb + (size_t)i * 4) = u;
    }
  } else {
    int i = (b - 1088 - nb_cvt) * 256 + tid;
    if (i < E) atomicAdd(&degi[dsts[i]], 1);
  }
}

// Single-block exclusive scan + dis = rsqrt(deg+1).
__global__ __launch_bounds__(1024) void k_scan_dis(const int* __restrict__ degi,
                                                   int* __restrict__ ptr,
                                                   float* __restrict__ dis, int n) {
  __shared__ int part[1024];
  const int tid = threadIdx.x;
  const int chunk = (n + 1023) / 1024;
  const int b = tid * chunk;
  const int e2 = min(n, b + chunk);
  int s = 0;
  for (int i = b; i < e2; ++i) {
    int d = degi[i];
    dis[i] = rsqrtf((float)d + 1.0f);
    s += d;
  }
  part[tid] = s;
  __syncthreads();
  for (int off = 1; off < 1024; off <<= 1) {
    int val = (tid >= off) ? part[tid - off] : 0;
    __syncthreads();
    part[tid] += val;
    __syncthreads();
  }
  int run = (tid == 0) ? 0 : part[tid - 1];
  for (int i = b; i < e2; ++i) {
    ptr[i] = run;
    run += degi[i];
  }
  if (tid == 1023) ptr[n] = run;
}

// Counting-sort fill: edges grouped by dst; store (src, dis[src]*dis[dst]).
__global__ void k_fill(const int* __restrict__ srcs, const int* __restrict__ dsts,
                       const int* __restrict__ ptr, const float* __restrict__ dis,
                       int* __restrict__ fillc,
                       int2* __restrict__ sc_s, int* __restrict__ dst_s,
                       int* __restrict__ perm_s, int E) {
  int e = blockIdx.x * 256 + threadIdx.x;
  if (e >= E) return;
  int d = dsts[e];
  int s = srcs[e];
  int pos = ptr[d] + atomicAdd(&fillc[d], 1);
  float c = dis[s] * dis[d];
  sc_s[pos] = make_int2(s, __float_as_int(c));
  dst_s[pos] = d;
  perm_s[pos] = e;
}

// Per-node CSR gather. FINALIZE: out = relu(acc + hw[v]*dis^2 + bias).
// INBF16: feat/hw bf16.  OUTBF16: write bf16 (FINALIZE path only).
template <int COLS, bool FINALIZE, bool INBF16, bool OUTBF16>
__global__ __launch_bounds__(256) void k_gather_agg(
    const void* __restrict__ featv, const int2* __restrict__ sc,
    const int* __restrict__ ptr, const float* __restrict__ dis,
    const void* __restrict__ hwv, const float* __restrict__ bias,
    void* __restrict__ outv, int n) {
  constexpr int V = COLS / 64;
  const int v = blockIdx.x * 4 + (threadIdx.x >> 6);
  if (v >= n) return;
  const int lane = threadIdx.x & 63;
  const int beg = ptr[v], end = ptr[v + 1];

  auto loadrow = [&](int s, float* f) {
    if constexpr (INBF16) {
      const ushort_t* feat = (const ushort_t*)featv;
      if constexpr (V == 4) {
        ushort4 u = *(const ushort4*)(feat + (size_t)s * COLS + lane * 4);
        f[0] = bf2f(u.x); f[1] = bf2f(u.y); f[2] = bf2f(u.z); f[3] = bf2f(u.w);
      } else {
        f[0] = bf2f(feat[(size_t)s * COLS + lane]);
      }
    } else {
      const float* feat = (const float*)featv;
      if constexpr (V == 4) {
        float4 q = *(const float4*)(feat + (size_t)s * COLS + lane * 4);
        f[0] = q.x; f[1] = q.y; f[2] = q.z; f[3] = q.w;
      } else {
        f[0] = feat[(size_t)s * COLS + lane];
      }
    }
  };

  float acc[V];
#pragma unroll
  for (int i = 0; i < V; ++i) acc[i] = 0.f;
  const int cnt = end - beg;
  const int2* scp = sc + beg;
  int i = 0;
  for (; i + 4 <= cnt; i += 4) {
    int2 s0 = scp[i], s1 = scp[i + 1], s2 = scp[i + 2], s3 = scp[i + 3];
    float f0[V], f1[V], f2[V], f3[V];
    loadrow(s0.x, f0); loadrow(s1.x, f1); loadrow(s2.x, f2); loadrow(s3.x, f3);
    float c0 = __int_as_float(s0.y), c1 = __int_as_float(s1.y);
    float c2 = __int_as_float(s2.y), c3 = __int_as_float(s3.y);
#pragma unroll
    for (int j = 0; j < V; ++j)
      acc[j] += f0[j] * c0 + f1[j] * c1 + f2[j] * c2 + f3[j] * c3;
  }
  for (; i < cnt; ++i) {
    int2 s0 = scp[i];
    float c0 = __int_as_float(s0.y);
    float f0[V];
    loadrow(s0.x, f0);
#pragma unroll
    for (int j = 0; j < V; ++j) acc[j] += f0[j] * c0;
  }
  if constexpr (FINALIZE) {
    const float dv = dis[v];
    float d2 = dv * dv;
    float h[V];
    if constexpr (INBF16) {
      const ushort_t* hw = (const ushort_t*)hwv;
      if constexpr (V == 4) {
        ushort4 u = *(const ushort4*)(hw + (size_t)v * COLS + lane * 4);
        h[0] = bf2f(u.x); h[1] = bf2f(u.y); h[2] = bf2f(u.z); h[3] = bf2f(u.w);
      } else {
        h[0] = bf2f(hw[(size_t)v * COLS + lane]);
      }
    } else {
      const float* hw = (const float*)hwv;
      if constexpr (V == 4) {
        float4 q = *(const float4*)(hw + (size_t)v * COLS + lane * 4);
        h[0] = q.x; h[1] = q.y; h[2] = q.z; h[3] = q.w;
      } else {
        h[0] = hw[(size_t)v * COLS + lane];
      }
    }
#pragma unroll
    for (int i2 = 0; i2 < V; ++i2)
      acc[i2] = fmaxf(acc[i2] + h[i2] * d2 + bias[lane * V + i2], 0.f);
  }
  if constexpr (OUTBF16) {
    ushort_t* op = (ushort_t*)outv + (size_t)v * COLS + lane * V;
    if constexpr (V == 4) {
      ushort4 u;
      u.x = f2bf(acc[0]); u.y = f2bf(acc[1]); u.z = f2bf(acc[2]); u.w = f2bf(acc[3]);
      *(ushort4*)op = u;
    } else {
      op[0] = f2bf(acc[0]);
    }
  } else {
    float* op = (float*)outv + (size_t)v * COLS + lane * V;
    if constexpr (V == 4) {
      *(float4*)op = make_float4(acc[0], acc[1], acc[2], acc[3]);
    } else {
      op[0] = acc[0];
    }
  }
}

// Generic node GEMM: out[r,:NOUT] = inA[r,:K] (+inB[r,:K]*dis[r]^2) @ Wp (+bias, relu)
// INA_BF16: inA is bf16 (raw staging copy; requires !COMPOSE).
template <int K, int NOUT, bool COMPOSE, bool RELUBIAS, bool OUTBF16, bool INA_BF16>
__global__ __launch_bounds__(256, 2) void gcn_gemm(
    const void* __restrict__ inAv, const float* __restrict__ inB,
    const float* __restrict__ dis,
    const unsigned short* __restrict__ Wp, const float* __restrict__ bias,
    void* __restrict__ outv, int out_stride, int nrows) {
  constexpr int NT = NOUT / 16;
  constexpr int NTW = NOUT / 64;
  __shared__ unsigned short s_in[64 * K];
  const int tid = threadIdx.x;
  const int r0 = blockIdx.x * 64;

  constexpr int C4R = K / 4;
  for (int idx = tid; idx < 64 * C4R; idx += 256) {
    int row = idx / C4R;
    int rem = idx - row * C4R;
    int grow = r0 + row;
    ushort4 b = make_ushort4(0, 0, 0, 0);
    if (grow < nrows) {
      if constexpr (INA_BF16) {
        b = *(const ushort4*)((const ushort_t*)inAv + (size_t)grow * K + rem * 4);
      } else {
        float4 v = *(const float4*)((const float*)inAv + (size_t)grow * K + rem * 4);
        if constexpr (COMPOSE) {
          float d = dis[grow];
          d *= d;
          float4 w2 = *(const float4*)&inB[(size_t)grow * K + rem * 4];
          v.x += w2.x * d; v.y += w2.y * d; v.z += w2.z * d; v.w += w2.w * d;
        }
        b.x = f2bf(v.x); b.y = f2bf(v.y); b.z = f2bf(v.z); b.w = f2bf(v.w);
      }
    }
    *(ushort4*)&s_in[row * K + ((rem ^ (row & 7)) * 4)] = b;
  }
  __syncthreads();

  const int lane = tid & 63, wid = tid >> 6;
  const int lr = lane & 15, lg = lane >> 4;
  f32x4 acc[4][NTW];
#pragma unroll
  for (int m = 0; m < 4; ++m)
#pragma unroll
    for (int n2 = 0; n2 < NTW; ++n2) acc[m][n2] = zero4();

#pragma unroll
  for (int kt = 0; kt < K / 32; ++kt) {
    bf16x8 a[4];
#pragma unroll
    for (int m = 0; m < 4; ++m) {
      int rA = m * 16 + lr;
      int c1 = (kt * 8 + lg) ^ (rA & 7);
      int c2 = (kt * 8 + lg + 4) ^ (rA & 7);
      union { bf16x8 v; ull_t q[2]; } u;
      u.q[0] = *(const ull_t*)&s_in[rA * K + c1 * 4];
      u.q[1] = *(const ull_t*)&s_in[rA * K + c2 * 4];
      a[m] = u.v;
    }
#pragma unroll
    for (int n2 = 0; n2 < NTW; ++n2) {
      int nt = wid * NTW + n2;
      bf16x8 b = *(const bf16x8*)&Wp[(((kt * NT + nt) * 64 + lane) * 8)];
#pragma unroll
      for (int m = 0; m < 4; ++m)
        acc[m][n2] = __builtin_amdgcn_mfma_f32_16x16x32_bf16(a[m], b, acc[m][n2], 0, 0, 0);
    }
  }

#pragma unroll
  for (int n2 = 0; n2 < NTW; ++n2) {
    int col = (wid * NTW + n2) * 16 + lr;
    float bv = 0.f;
    if (RELUBIAS) bv = bias[col];
#pragma unroll
    for (int m = 0; m < 4; ++m) {
#pragma unroll
      for (int r = 0; r < 4; ++r) {
        int grow = r0 + m * 16 + lg * 4 + r;
        if (grow < nrows) {
          float v = acc[m][n2][r];
          if (RELUBIAS) v = fmaxf(v + bv, 0.f);
          if constexpr (OUTBF16) {
            ((ushort_t*)outv)[(size_t)grow * out_stride + col] = f2bf(v);
          } else {
            ((float*)outv)[(size_t)grow * out_stride + col] = v;
          }
        }
      }
    }
  }
}

// conv2 GEMM: K=512 where cols 0-255 come from h2a (bf16, raw copy) and
// cols 256-511 from h2b (f32, cvt). Out bf16 (hw2b).
__global__ __launch_bounds__(256, 2) void gcn_gemm_mix(
    const ushort_t* __restrict__ h2a, const float* __restrict__ h2b,
    const unsigned short* __restrict__ Wp, ushort_t* __restrict__ outv,
    int nrows) {
  constexpr int K = 512, NT = 16, NTW = 4;
  __shared__ unsigned short s_in[64 * K];
  const int tid = threadIdx.x;
  const int r0 = blockIdx.x * 64;

  for (int idx = tid; idx < 64 * 128; idx += 256) {
    int row = idx >> 7;
    int rem = idx & 127;
    int grow = r0 + row;
    ushort4 b = make_ushort4(0, 0, 0, 0);
    if (grow < nrows) {
      if (rem < 64) {
        b = *(const ushort4*)&h2a[(size_t)grow * 256 + rem * 4];
      } else {
        float4 v = *(const float4*)&h2b[(size_t)grow * 256 + (rem - 64) * 4];
        b.x = f2bf(v.x); b.y = f2bf(v.y); b.z = f2bf(v.z); b.w = f2bf(v.w);
      }
    }
    *(ushort4*)&s_in[row * K + ((rem ^ (row & 7)) * 4)] = b;
  }
  __syncthreads();

  const int lane = tid & 63, wid = tid >> 6;
  const int lr = lane & 15, lg = lane >> 4;
  f32x4 acc[4][NTW];
#pragma unroll
  for (int m = 0; m < 4; ++m)
#pragma unroll
    for (int n2 = 0; n2 < NTW; ++n2) acc[m][n2] = zero4();

#pragma unroll
  for (int kt = 0; kt < K / 32; ++kt) {
    bf16x8 a[4];
#pragma unroll
    for (int m = 0; m < 4; ++m) {
      int rA = m * 16 + lr;
      int c1 = (kt * 8 + lg) ^ (rA & 7);
      int c2 = (kt * 8 + lg + 4) ^ (rA & 7);
      union { bf16x8 v; ull_t q[2]; } u;
      u.q[0] = *(const ull_t*)&s_in[rA * K + c1 * 4];
      u.q[1] = *(const ull_t*)&s_in[rA * K + c2 * 4];
      a[m] = u.v;
    }
#pragma unroll
    for (int n2 = 0; n2 < NTW; ++n2) {
      int nt = wid * NTW + n2;
      bf16x8 b = *(const bf16x8*)&Wp[(((kt * NT + nt) * 64 + lane) * 8)];
#pragma unroll
      for (int m = 0; m < 4; ++m)
        acc[m][n2] = __builtin_amdgcn_mfma_f32_16x16x32_bf16(a[m], b, acc[m][n2], 0, 0, 0);
    }
  }

#pragma unroll
  for (int n2 = 0; n2 < NTW; ++n2) {
    int col = (wid * NTW + n2) * 16 + lr;
#pragma unroll
    for (int m = 0; m < 4; ++m) {
#pragma unroll
      for (int r = 0; r < 4; ++r) {
        int grow = r0 + m * 16 + lg * 4 + r;
        if (grow < nrows)
          outv[(size_t)grow * 256 + col] = f2bf(acc[m][n2][r]);
      }
    }
  }
}

// Fused EdgeConv on dst-sorted edges. 128-edge tiles (R12 structure).
__global__ __launch_bounds__(512, 4) void k_edgeconv(
    const float* __restrict__ x, const float* __restrict__ ea,
    const int2* __restrict__ sc_s, const int* __restrict__ dst_s,
    const int* __restrict__ perm_s,
    const unsigned short* __restrict__ W1p, const float* __restrict__ b1,
    const unsigned short* __restrict__ W2p, const float* __restrict__ b2,
    float* __restrict__ h2b, int E) {
  __shared__ unsigned short s_buf[256 * 136];
  __shared__ int s_src[128], s_dst[128], s_perm[128];
  __shared__ ull_t s_mask[2];
  const int tid = threadIdx.x;
  const int e0 = blockIdx.x * 128;
  const int lane = tid & 63, wid = tid >> 6;
  if (tid < 128) {
    int e = e0 + tid;
    s_src[tid] = (e < E) ? sc_s[e].x : 0;
    s_dst[tid] = (e < E) ? dst_s[e] : 0;
    s_perm[tid] = (e < E) ? perm_s[e] : 0;
  }
  __syncthreads();
  if (wid < 2) {
    int r = wid * 64 + lane;
    bool chg = (r > 0) && (s_dst[r] != s_dst[r - 1]);
    ull_t m = __ballot(chg);
    if (lane == 0) s_mask[wid] = m;
  }
#pragma unroll
  for (int seg = 0; seg < 3; ++seg) {
#pragma unroll
    for (int it = 0; it < 4; ++it) {
      int idx = it * 512 + tid;
      int ei = idx >> 4;
      int q = idx & 15;
      const float* row;
      if (seg == 0) row = x + (unsigned)s_dst[ei] * 64u;
      else if (seg == 1) row = x + (unsigned)s_src[ei] * 64u;
      else row = ea + (unsigned)s_perm[ei] * 64u;
      float4 v = make_float4(0.f, 0.f, 0.f, 0.f);
      if (e0 + ei < E) v = *(const float4*)(row + q * 4);
      ushort4 b;
      b.x = f2bf(v.x); b.y = f2bf(v.y); b.z = f2bf(v.z); b.w = f2bf(v.w);
      int chunk = (seg * 16 + q) ^ (ei & 7);
      *(ushort4*)&s_buf[ei * 192 + chunk * 4] = b;
    }
  }
  __syncthreads();

  const int wr = wid >> 2;
  const int wc = wid & 3;
  const int lr = lane & 15, lg = lane >> 4;
  f32x4 acc[4][4];
#pragma unroll
  for (int m = 0; m < 4; ++m)
#pragma unroll
    for (int n2 = 0; n2 < 4; ++n2) acc[m][n2] = zero4();

  // GEMM1: K=192 -> hidden 256
#pragma unroll
  for (int kt = 0; kt < 6; ++kt) {
    bf16x8 a[4];
#pragma unroll
    for (int m = 0; m < 4; ++m) {
      int rA = wr * 64 + m * 16 + lr;
      int rr = rA & 7;
      union { bf16x8 v; ull_t q[2]; } u;
      u.q[0] = *(const ull_t*)&s_buf[rA * 192 + ((kt * 8 + lg) ^ rr) * 4];
      u.q[1] = *(const ull_t*)&s_buf[rA * 192 + ((kt * 8 + lg + 4) ^ rr) * 4];
      a[m] = u.v;
    }
#pragma unroll
    for (int n2 = 0; n2 < 4; ++n2) {
      int nt = wc * 4 + n2;
      bf16x8 b = *(const bf16x8*)&W1p[(((kt * 16 + nt) * 64 + lane) * 8)];
#pragma unroll
      for (int m = 0; m < 4; ++m)
        acc[m][n2] = __builtin_amdgcn_mfma_f32_16x16x32_bf16(a[m], b, acc[m][n2], 0, 0, 0);
    }
  }
  __syncthreads();

  // hid = relu(acc1 + b1) bf16 -> s_buf[row][256] COL-PERMUTED, b64 writes.
  {
    float b1v[4];
#pragma unroll
    for (int n2 = 0; n2 < 4; ++n2) b1v[n2] = b1[(wc * 4 + n2) * 16 + lr];
#pragma unroll
    for (int m = 0; m < 4; ++m) {
#pragma unroll
      for (int r = 0; r < 4; ++r) {
        int row = wr * 64 + m * 16 + lg * 4 + r;
        union { ushort_t h[4]; ull_t q; } pk;
        pk.h[0] = f2bf(fmaxf(acc[m][0][r] + b1v[0], 0.f));
        pk.h[1] = f2bf(fmaxf(acc[m][1][r] + b1v[1], 0.f));
        pk.h[2] = f2bf(fmaxf(acc[m][2][r] + b1v[2], 0.f));
        pk.h[3] = f2bf(fmaxf(acc[m][3][r] + b1v[3], 0.f));
        int chunk = (wc * 16 + lr) ^ (row & 7);
        *(ull_t*)&s_buf[row * 256 + chunk * 4] = pk.q;
      }
    }
  }
  __syncthreads();

  // GEMM2: K=256 (permuted k-space; W2p pack PERMK-compensates)
#pragma unroll
  for (int m = 0; m < 4; ++m)
#pragma unroll
    for (int n2 = 0; n2 < 4; ++n2) acc[m][n2] = zero4();
#pragma unroll
  for (int kt = 0; kt < 8; ++kt) {
    bf16x8 a[4];
#pragma unroll
    for (int m = 0; m < 4; ++m) {
      int rA = wr * 64 + m * 16 + lr;
      int rr = rA & 7;
      union { bf16x8 v; ull_t q[2]; } u;
      u.q[0] = *(const ull_t*)&s_buf[rA * 256 + ((kt * 8 + lg) ^ rr) * 4];
      u.q[1] = *(const ull_t*)&s_buf[rA * 256 + ((kt * 8 + lg + 4) ^ rr) * 4];
      a[m] = u.v;
    }
#pragma unroll
    for (int n2 = 0; n2 < 4; ++n2) {
      int nt = wc * 4 + n2;
      bf16x8 b = *(const bf16x8*)&W2p[(((kt * 16 + nt) * 64 + lane) * 8)];
#pragma unroll
      for (int m = 0; m < 4; ++m)
        acc[m][n2] = __builtin_amdgcn_mfma_f32_16x16x32_bf16(a[m], b, acc[m][n2], 0, 0, 0);
    }
  }
  __syncthreads();

  // m = relu(acc2 + b2) -> TRANSPOSED [col][136] as packed b64
#pragma unroll
  for (int n2 = 0; n2 < 4; ++n2) {
    int col = (wc * 4 + n2) * 16 + lr;
    float bv = b2[col];
#pragma unroll
    for (int m = 0; m < 4; ++m) {
      int rbase = wr * 64 + m * 16 + lg * 4;
      union { ushort_t h[4]; ull_t q; } pk;
#pragma unroll
      for (int r = 0; r < 4; ++r) {
        int row = rbase + r;
        float v = (e0 + row < E) ? fmaxf(acc[m][n2][r] + bv, 0.f) : 0.f;
        pk.h[r] = f2bf(v);
      }
      *(ull_t*)&s_buf[col * 136 + rbase] = pk.q;
    }
  }
  __syncthreads();

  // Segmented max scan in u16 domain.
  {
    const int col = tid & 255;
    const int half = tid >> 8;
    const int rbeg = half * 64;
    const ull_t mask = s_mask[half];
    unsigned int run = 0;
    int segstart = rbeg;
#pragma unroll
    for (int i = 0; i < 8; ++i) {
      u16x8 pack = *(const u16x8*)&s_buf[col * 136 + rbeg + i * 8];
#pragma unroll
      for (int r2 = 0; r2 < 8; ++r2) {
        int rloc = i * 8 + r2;
        if ((mask >> rloc) & 1ull) {
          if (run > 0)
            atomicMax((int*)h2b + ((unsigned)s_dst[segstart] * 256u + col),
                      (int)(run << 16));
          run = 0;
          segstart = rbeg + rloc;
        }
        run = max(run, (unsigned int)pack[r2]);
      }
    }
    if (run > 0)
      atomicMax((int*)h2b + ((unsigned)s_dst[segstart] * 256u + col),
                (int)(run << 16));
  }
}

// Head MLP: wave-per-node, weights (except W2) staged in LDS.
__global__ __launch_bounds__(256) void k_head(
    const float* __restrict__ x, const float* __restrict__ out3,
    const float* __restrict__ W1, const float* __restrict__ b1,
    const float* __restrict__ W2, const float* __restrict__ b2,
    const float* __restrict__ W3, const float* __restrict__ b3,
    const float* __restrict__ W4, const float* __restrict__ b4,
    float* __restrict__ out, int n) {
  __shared__ float sW1[128 * 64];
  __shared__ float sW3[128 * 32];
  __shared__ float sW4[32 * 2];
  __shared__ float sb1[64], sb2[128], sb3[32], sb4[2];
  __shared__ float sbuf[4][352];
  const int tid = threadIdx.x;
  for (int i = tid; i < 128 * 64; i += 256) sW1[i] = W1[i];
  for (int i = tid; i < 128 * 32; i += 256) sW3[i] = W3[i];
  if (tid < 64) sW4[tid] = W4[tid];
  if (tid < 64) sb1[tid] = b1[tid];
  if (tid < 128) sb2[tid] = b2[tid];
  if (tid < 32) sb3[tid] = b3[tid];
  if (tid < 2) sb4[tid] = b4[tid];
  __syncthreads();
  const int wid = tid >> 6, lane = tid & 63;
  float* B = sbuf[wid];
  const int per = gridDim.x * 4;
  const int iters = (n + per - 1) / per;
  for (int it = 0; it < iters; ++it) {
    const int node = it * per + blockIdx.x * 4 + wid;
    const bool act = node < n;
    if (act) {
      B[lane] = x[(size_t)node * 64 + lane];
      B[64 + lane] = out3[(size_t)node * 64 + lane];
    }
    __syncthreads();
    if (act) {
      float o = sb1[lane];
#pragma unroll 8
      for (int k = 0; k < 128; ++k) o += B[k] * sW1[k * 64 + lane];
      B[128 + lane] = softplusf(o);
    }
    __syncthreads();
    if (act) {
      float o0 = sb2[lane], o1 = sb2[64 + lane];
#pragma unroll 8
      for (int k = 0; k < 64; ++k) {
        float v = B[128 + k];
        o0 += v * W2[k * 128 + lane];
        o1 += v * W2[k * 128 + 64 + lane];
      }
      B[192 + lane] = softplusf(o0);
      B[256 + lane] = softplusf(o1);
    }
    __syncthreads();
    if (act && lane < 32) {
      float o = sb3[lane];
#pragma unroll 8
      for (int k = 0; k < 128; ++k) o += B[192 + k] * sW3[k * 32 + lane];
      B[320 + lane] = softplusf(o);
    }
    __syncthreads();
    if (act && lane < 2) {
      float o = sb4[lane];
#pragma unroll
      for (int k = 0; k < 32; ++k) o += B[320 + k] * sW4[k * 2 + lane];
      out[(size_t)lane * n + node] = o;
    }
    __syncthreads();
  }
}

static inline size_t alignup(size_t v) { return (v + 255) & ~(size_t)255; }

extern "C" void kernel_launch(void* const* d_in, const int* in_sizes, int n_in,
                              void* d_out, int out_size, void* d_ws, size_t ws_size,
                              hipStream_t stream) {
  const float* x = (const float*)d_in[0];
  const int* ei = (const int*)d_in[1];
  const float* ea = (const float*)d_in[2];
  const float* c1W = (const float*)d_in[3];
  const float* c1b = (const float*)d_in[4];
  const float* eW1 = (const float*)d_in[5];
  const float* eb1 = (const float*)d_in[6];
  const float* eW2 = (const float*)d_in[7];
  const float* eb2 = (const float*)d_in[8];
  const float* c2W = (const float*)d_in[9];
  const float* c2b = (const float*)d_in[10];
  const float* c3W = (const float*)d_in[11];
  const float* c3b = (const float*)d_in[12];
  const float* l1W = (const float*)d_in[13];
  const float* l1b = (const float*)d_in[14];
  const float* l2W = (const float*)d_in[15];
  const float* l2b = (const float*)d_in[16];
  const float* l3W = (const float*)d_in[17];
  const float* l3b = (const float*)d_in[18];
  const float* l4W = (const float*)d_in[19];
  const float* l4b = (const float*)d_in[20];
  const int n = in_sizes[0] / 64;
  const int E = in_sizes[1] / 2;
  const int* srcs = ei;
  const int* dsts = ei + E;

  char* w = (char*)d_ws;
  auto alloc = [&](size_t bytes) {
    char* p = w;
    w += alignup(bytes);
    return p;
  };
  float* dis = (float*)alloc((size_t)n * 4);
  int* degi = (int*)alloc((size_t)n * 4);
  int* ptr = (int*)alloc((size_t)(n + 1) * 4);
  int* fillc = (int*)alloc((size_t)n * 4);
  int2* sc_s = (int2*)alloc((size_t)E * 8);
  int* dst_s = (int*)alloc((size_t)E * 4);
  int* perm_s = (int*)alloc((size_t)E * 4);
  float* agg1 = (float*)alloc((size_t)n * 64 * 4);
  ushort_t* h2a = (ushort_t*)alloc((size_t)n * 256 * 2);   // conv1 out, bf16
  float* h2b = (float*)alloc((size_t)n * 256 * 4);         // edgeconv max, f32
  ushort_t* hw2b = (ushort_t*)alloc((size_t)n * 256 * 2);  // bf16
  ushort_t* out2b = (ushort_t*)alloc((size_t)n * 256 * 2); // conv2 out, bf16
  ushort_t* hw3b = (ushort_t*)alloc((size_t)n * 64 * 2);   // bf16
  float* out3 = (float*)alloc((size_t)n * 64 * 4);
  ushort_t* xb = (ushort_t*)alloc((size_t)n * 64 * 2);     // x as bf16
  unsigned short* p_c1 = (unsigned short*)alloc(64 * 256 * 2);
  unsigned short* p_e1 = (unsigned short*)alloc(192 * 256 * 2);
  unsigned short* p_e2 = (unsigned short*)alloc(256 * 256 * 2);  // PERMK
  unsigned short* p_c2 = (unsigned short*)alloc(512 * 256 * 2);
  unsigned short* p_c3 = (unsigned short*)alloc(256 * 64 * 2);

  hipMemsetAsync(degi, 0, (size_t)n * 4, stream);
  hipMemsetAsync(fillc, 0, (size_t)n * 4, stream);
  hipMemsetAsync(h2b, 0, (size_t)n * 256 * 4, stream);

  const int n4 = n * 16;
  const int nb_cvt = (n4 + 255) / 256;
  const int nb_deg = (E + 255) / 256;
  k_prologue<<<1088 + nb_cvt + nb_deg, 256, 0, stream>>>(
      c1W, p_c1, eW1, p_e1, eW2, p_e2, c2W, p_c2, c3W, p_c3,
      x, xb, dsts, degi, n4, E, nb_cvt);

  k_scan_dis<<<1, 1024, 0, stream>>>(degi, ptr, dis, n);
  k_fill<<<(E + 255) / 256, 256, 0, stream>>>(srcs, dsts, ptr, dis, fillc,
                                              sc_s, dst_s, perm_s, E);

  const int ablocks = (n + 3) / 4;
  const int gblocks = (n + 63) / 64;

  // conv1: gather-aggregate xb (bf16), then GEMM (bf16 out -> h2a)
  k_gather_agg<64, false, true, false><<<ablocks, 256, 0, stream>>>(
      xb, sc_s, ptr, dis, nullptr, nullptr, agg1, n);
  gcn_gemm<64, 256, true, true, true, false><<<gblocks, 256, 0, stream>>>(
      agg1, x, dis, p_c1, c1b, h2a, 256, n);

  // EdgeConv -> h2b (128-edge tiles)
  k_edgeconv<<<(E + 127) / 128, 512, 0, stream>>>(x, ea, sc_s, dst_s, perm_s,
                                                  p_e1, eb1, p_e2, eb2, h2b, E);

  // conv2: mixed-source GEMM -> hw2b, then gather+finalize (bf16 out -> out2b)
  gcn_gemm_mix<<<gblocks, 256, 0, stream>>>(h2a, h2b, p_c2, hw2b, n);
  k_gather_agg<256, true, true, true><<<ablocks, 256, 0, stream>>>(
      hw2b, sc_s, ptr, dis, hw2b, c2b, out2b, n);

  // conv3: bf16-input GEMM (raw staging) -> hw3b, then gather+finalize (f32 out)
  gcn_gemm<256, 64, false, false, true, true><<<gblocks, 256, 0, stream>>>(
      out2b, nullptr, nullptr, p_c3, nullptr, hw3b, 64, n);
  k_gather_agg<64, true, true, false><<<ablocks, 256, 0, stream>>>(
      hw3b, sc_s, ptr, dis, hw3b, c3b, out3, n);

  k_head<<<1250, 256, 0, stream>>>(x, out3, l1W, l1b, l2W, l2b, l3W, l3b, l4W, l4b,
                                   (float*)d_out, n);
}